// Round 4
// baseline (422.167 us; speedup 1.0000x reference)
//
#include <hip/hip_runtime.h>
#include <stdint.h>
#include <stddef.h>

// ClusteredPrototypeLoss — MI355X, round 4.
// 2 launches: stageA (1800 blocks, coalesced row-extract -> bricks, resets
// barrier counter) -> mega (256 persistent blocks: stageB + 3x(W->update) +
// final W + loss(+argmin) + finalize, with 9 device-scope grid barriers).
// All phase bodies bit-identical to the round-3 passing kernels.

namespace {

constexpr int kB = 2;
constexpr int kNT = 1000, kNP = 125, kNZ = 1000;
constexpr float kTempT = 0.033f, kTempS = 0.066f;
constexpr double kSig2 = (128.0 / 2.355) * (128.0 / 2.355);
constexpr float kTwoSig2 = (float)(2.0 * kSig2);
constexpr int kGrid = 256;   // mega grid: 1 block/CU, co-resident by construction

// ---------------- host: replicate np.random.default_rng(0).integers(0,8,6) ----------------
struct Pcg64 {
  __uint128_t state, inc;
  static __uint128_t mult() {
    return (((__uint128_t)2549297995355413924ULL) << 64) | 4865540595714422341ULL;
  }
  void step() { state = state * mult() + inc; }
  void seed(__uint128_t initstate, __uint128_t initseq) {
    state = 0; inc = (initseq << 1) | 1; step(); state += initstate; step();
  }
  uint64_t next64() {
    step();
    uint64_t xo = (uint64_t)(state >> 64) ^ (uint64_t)state;
    unsigned rot = (unsigned)((uint64_t)(state >> 122) & 63u);
    return (xo >> rot) | (xo << ((64u - rot) & 63u));
  }
};

static inline uint32_t ss_hashmix(uint32_t v, uint32_t& hc) {
  v ^= hc; hc *= 0x931e8875u; v *= hc; v ^= v >> 16; return v;
}
static inline uint32_t ss_mix(uint32_t x, uint32_t y) {
  uint32_t r = (0xca01f9ddu * x) ^ (0x4973f715u * y);
  r ^= r >> 16; return r;
}

static void numpy_jitter_seed0(int jit[6]) {
  uint32_t pool[4];
  uint32_t hc = 0x43b0d7e5u;  // INIT_A
  for (int i = 0; i < 4; ++i) pool[i] = ss_hashmix(0u, hc);
  for (int s = 0; s < 4; ++s)
    for (int d = 0; d < 4; ++d)
      if (s != d) pool[d] = ss_mix(pool[d], ss_hashmix(pool[s], hc));
  uint32_t w32[8];
  uint32_t hb = 0x8b51f9ddu;  // INIT_B
  for (int i = 0; i < 8; ++i) {
    uint32_t dv = pool[i & 3];
    dv ^= hb; hb *= 0x58f38dedu; dv *= hb; dv ^= dv >> 16;
    w32[i] = dv;
  }
  uint64_t w64[4];
  for (int i = 0; i < 4; ++i)
    w64[i] = (uint64_t)w32[2 * i] | ((uint64_t)w32[2 * i + 1] << 32);
  Pcg64 rng;
  rng.seed((((__uint128_t)w64[0]) << 64) | w64[1],
           (((__uint128_t)w64[2]) << 64) | w64[3]);
  for (int i = 0; i < 6; ++i) jit[i] = (int)(rng.next64() & 7ULL);
}

// ---------------- device helpers ----------------

struct AxisTap { int a, b; float w; };

__device__ inline AxisTap axis_tap(int i, float sc, int S) {
  float src = (i + 0.5f) * sc - 0.5f;
  float f = floorf(src);
  float w = src - f;
  int a = (int)f; a = a < 0 ? 0 : (a > S - 1 ? S - 1 : a);
  int b = (a + 1 > S - 1) ? S - 1 : a + 1;
  return {a, b, w};
}

__device__ inline float trilerp_vals(float v000, float v100, float v010, float v110,
                                     float v001, float v101, float v011, float v111,
                                     float w0, float w1, float w2) {
  float t00 = v000 * (1.0f - w0) + v100 * w0;
  float t10 = v010 * (1.0f - w0) + v110 * w0;
  float t01 = v001 * (1.0f - w0) + v101 * w0;
  float t11 = v011 * (1.0f - w0) + v111 * w0;
  float u0 = t00 * (1.0f - w1) + t10 * w1;
  float u1 = t01 * (1.0f - w1) + t11 * w1;
  return u0 * (1.0f - w2) + u1 * w2;
}

__device__ inline void coord_exact(int i, int j, int k,
                                   float sc0, float sc1, float sc2,
                                   int s0, int s1, int s2, int S0, int S1, int S2,
                                   float& c0o, float& c1o, float& c2o) {
#pragma clang fp contract(off)
  float src0 = (i + 0.5f) * sc0 - 0.5f;
  float f0 = floorf(src0); float w0 = src0 - f0;
  int a0 = (int)f0; a0 = a0 < 0 ? 0 : (a0 > S0 - 1 ? S0 - 1 : a0);
  int b0 = (a0 + 1 > S0 - 1) ? S0 - 1 : a0 + 1;

  float src1 = (j + 0.5f) * sc1 - 0.5f;
  float f1 = floorf(src1); float w1 = src1 - f1;
  int a1 = (int)f1; a1 = a1 < 0 ? 0 : (a1 > S1 - 1 ? S1 - 1 : a1);
  int b1 = (a1 + 1 > S1 - 1) ? S1 - 1 : a1 + 1;

  float src2 = (k + 0.5f) * sc2 - 0.5f;
  float f2 = floorf(src2); float w2 = src2 - f2;
  int a2 = (int)f2; a2 = a2 < 0 ? 0 : (a2 > S2 - 1 ? S2 - 1 : a2);
  int b2 = (a2 + 1 > S2 - 1) ? S2 - 1 : a2 + 1;

  float v0 = (float)(s0 + a0), v1 = (float)(s0 + b0);
  float c0 = v0 * (1.0f - w0) + v1 * w0;
  c0 = c0 * (1.0f - w1) + c0 * w1;
  c0 = c0 * (1.0f - w2) + c0 * w2;

  float g0 = (float)(s1 + a1), g1 = (float)(s1 + b1);
  float gA = g0 * (1.0f - w0) + g0 * w0;
  float gB = g1 * (1.0f - w0) + g1 * w0;
  float c1 = gA * (1.0f - w1) + gB * w1;
  c1 = c1 * (1.0f - w2) + c1 * w2;

  float h0 = (float)(s2 + a2), h1 = (float)(s2 + b2);
  float hA = h0 * (1.0f - w0) + h0 * w0;
  float hB = h1 * (1.0f - w0) + h1 * w0;
  hA = hA * (1.0f - w1) + hA * w1;
  hB = hB * (1.0f - w1) + hB * w1;
  float c2 = hA * (1.0f - w2) + hB * w2;

  c0o = c0; c1o = c1; c2o = c2;
}

__device__ inline void argmin_rowT(float zx, float zy, float zz,
                                   const float* ct0, const float* ct1, const float* ct2,
                                   int lane, float& best, int& bidx) {
#pragma clang fp contract(off)
  best = 3.4e38f; bidx = 0x7fffffff;
  for (int i = 0; i < 16; ++i) {
    float dx = zx - ct0[i * 64 + lane];
    float dy = zy - ct1[i * 64 + lane];
    float dz = zz - ct2[i * 64 + lane];
    float q0 = dx * dx, q1 = dy * dy, q2 = dz * dz;
    float d = sqrtf((q0 + q1) + q2);
    int n = lane * 16 + i;
    if (d < best) { best = d; bidx = n; }
  }
  for (int o = 32; o; o >>= 1) {
    float ob = __shfl_xor(best, o, 64);
    int oi = __shfl_xor(bidx, o, 64);
    if (ob < best || (ob == best && oi < bidx)) { best = ob; bidx = oi; }
  }
}

// Monotonic device-scope grid barrier (cnt pre-zeroed by stageA; grid=kGrid).
__device__ inline void grid_barrier(int* cnt, int gen) {
  __syncthreads();
  if (threadIdx.x == 0) {
    __threadfence();                 // release all prior writes device-wide
    atomicAdd(cnt, 1);               // device-scope by default
    int target = kGrid * gen;
    while (__hip_atomic_load(cnt, __ATOMIC_RELAXED, __HIP_MEMORY_SCOPE_AGENT) < target) {
      __builtin_amdgcn_s_sleep(2);
    }
    __threadfence();                 // acquire
  }
  __syncthreads();
}

// ---------------- kernels ----------------

// Stage A: extract corner-planes into channel-last bricks + reset barrier cnt.
__global__ __launch_bounds__(256) void stageA_kernel(
    const float* __restrict__ emb_t, const float* __restrict__ emb_s,
    float* __restrict__ Bt, float* __restrict__ Bs, float* __restrict__ Bp,
    int* __restrict__ cnt,
    int j0, int j2, int j4, int S0, int S1, int S2,
    float scZ0, float scZ1, float scZ2) {
  if (blockIdx.x == 0 && threadIdx.x == 0) atomicExch(cnt, 0);
  int idx = blockIdx.x;
  const float* src; float* brick;
  int b, xi, yi, Xb, Yb, Zb;
  float sc0, sc1, sc2; int Sa0, Sa1, Sa2; int o0, o1, o2;
  if (idx < 800) {            // targets: emb_t, r=10, sc=8
    src = emb_t; brick = Bt; b = idx / 400;
    int r = idx % 400; xi = r / 20; yi = r % 20;
    Xb = Yb = Zb = 20; sc0 = sc1 = sc2 = 8.0f;
    Sa0 = Sa1 = Sa2 = 80; o0 = o1 = o2 = 0;
  } else if (idx < 1600) {    // source: emb_s, jittered
    src = emb_s; brick = Bs; int r = idx - 800; b = r / 400;
    r %= 400; xi = r / 20; yi = r % 20;
    Xb = Yb = Zb = 20; sc0 = scZ0; sc1 = scZ1; sc2 = scZ2;
    Sa0 = S0; Sa1 = S1; Sa2 = S2; o0 = j0; o1 = j2; o2 = j4;
  } else {                    // protos: emb_t, r=5, sc=16
    src = emb_t; brick = Bp; int r = idx - 1600; b = r / 100;
    r %= 100; xi = r / 10; yi = r % 10;
    Xb = Yb = Zb = 10; sc0 = sc1 = sc2 = 16.0f;
    Sa0 = Sa1 = Sa2 = 80; o0 = o1 = o2 = 0;
  }
  AxisTap tx = axis_tap(xi >> 1, sc0, Sa0);
  int x = o0 + ((xi & 1) ? tx.b : tx.a);
  AxisTap ty = axis_tap(yi >> 1, sc1, Sa1);
  int y = o1 + ((yi & 1) ? ty.b : ty.a);

  __shared__ int zg[20];
  __shared__ float ztile[20][64];
  if (threadIdx.x < (unsigned)Zb) {
    AxisTap tz = axis_tap((int)threadIdx.x >> 1, sc2, Sa2);
    zg[threadIdx.x] = o2 + ((threadIdx.x & 1) ? tz.b : tz.a);
  }
  __syncthreads();

  int c = threadIdx.x >> 2, seg = threadIdx.x & 3;
  const float* row = src + ((size_t)(b * 64 + c)) * 512000 + ((size_t)x * 80 + y) * 80;
  for (int zi = seg; zi < Zb; zi += 4) ztile[zi][c] = row[zg[zi]];
  __syncthreads();

  float* outp = brick + (((size_t)(b * Xb + xi) * Yb + yi) * Zb) * 64;
  for (int o = threadIdx.x; o < Zb * 64; o += 256) outp[o] = ztile[o >> 6][o & 63];
}

// Mega kernel: stageB + 3x(W -> update) + final W + loss(+argmin) + finalize.
__global__ __launch_bounds__(256) void mega_kernel(
    const float* __restrict__ Bt, const float* __restrict__ Bs,
    const float* __restrict__ Bp,
    float* __restrict__ EMB_TS, float* __restrict__ EMB_TN,
    float* __restrict__ EMB_ZN, float* __restrict__ EMB_PN,
    float* __restrict__ COORD_P, float* __restrict__ COORD_T,
    float* __restrict__ COORD_Z, float* __restrict__ W,
    float* __restrict__ PART, float* __restrict__ out, int* __restrict__ cnt,
    int j0, int j2, int j4, int S0, int S1, int S2,
    float scZ0, float scZ1, float scZ2) {
  __shared__ float pnT[64 * 129];
  __shared__ float ctT0[1024], ctT1[1024], ctT2[1024];
  __shared__ float en[4][64];
  __shared__ float cpx[128], cpy[128], cpz[128];
  __shared__ float sE[4][64];
  __shared__ float sC[4][3];
  __shared__ float sD[4];
  __shared__ float sR[4], sM[4];

  const int blk = blockIdx.x;
  const int wv = threadIdx.x >> 6, lane = threadIdx.x & 63;
  int gen = 0;

  // ---- phase 0: stageB sampling (bit-identical unit bodies) ----
  for (int wid = blk * 4 + wv; wid < 4250; wid += kGrid * 4) {
    if (wid < 250) {
      int b = wid / 125, p = wid % 125;
      int i = p / 25, jj = (p / 5) % 5, k = p % 5;
      AxisTap t0 = axis_tap(i, 16.0f, 80), t1 = axis_tap(jj, 16.0f, 80), t2 = axis_tap(k, 16.0f, 80);
      const float* br = Bp + (((size_t)(b * 10 + 2 * i) * 10 + 2 * jj) * 10 + 2 * k) * 64 + lane;
      const int DX = 10 * 10 * 64, DY = 10 * 64, DZ = 64;
      float x = trilerp_vals(br[0], br[DX], br[DY], br[DX + DY],
                             br[DZ], br[DX + DZ], br[DY + DZ], br[DX + DY + DZ],
                             t0.w, t1.w, t2.w);
      float ss = x * x;
      for (int o = 32; o; o >>= 1) ss += __shfl_xor(ss, o, 64);
      float nrm = sqrtf(ss);
      EMB_PN[((size_t)b * kNP + p) * 64 + lane] = x / fmaxf(nrm, 1e-12f);
      if (lane == 0) {
        float c0, c1, c2;
        coord_exact(i, jj, k, 16.0f, 16.0f, 16.0f, 0, 0, 0, 80, 80, 80, c0, c1, c2);
        size_t o3 = ((size_t)b * kNP + p) * 3;
        COORD_P[o3] = c0; COORD_P[o3 + 1] = c1; COORD_P[o3 + 2] = c2;
      }
    } else if (wid < 2250) {
      int idx = wid - 250;
      int b = idx / 1000, n = idx % 1000;
      int i = n / 100, jj = (n / 10) % 10, k = n % 10;
      AxisTap t0 = axis_tap(i, 8.0f, 80), t1 = axis_tap(jj, 8.0f, 80), t2 = axis_tap(k, 8.0f, 80);
      const float* br = Bt + (((size_t)(b * 20 + 2 * i) * 20 + 2 * jj) * 20 + 2 * k) * 64 + lane;
      const int DX = 20 * 20 * 64, DY = 20 * 64, DZ = 64;
      float x = trilerp_vals(br[0], br[DX], br[DY], br[DX + DY],
                             br[DZ], br[DX + DZ], br[DY + DZ], br[DX + DY + DZ],
                             t0.w, t1.w, t2.w);
      EMB_TS[((size_t)b * kNT + n) * 64 + lane] = x;
      float ss = x * x;
      for (int o = 32; o; o >>= 1) ss += __shfl_xor(ss, o, 64);
      float nrm = sqrtf(ss);
      EMB_TN[((size_t)b * kNT + n) * 64 + lane] = x / fmaxf(nrm, 1e-12f);
      if (lane == 0) {
        float c0, c1, c2;
        coord_exact(i, jj, k, 8.0f, 8.0f, 8.0f, 0, 0, 0, 80, 80, 80, c0, c1, c2);
        size_t o3 = ((size_t)b * kNT + n) * 3;
        COORD_T[o3] = c0; COORD_T[o3 + 1] = c1; COORD_T[o3 + 2] = c2;
      }
    } else {
      int idx = wid - 2250;
      int b = idx / 1000, n = idx % 1000;
      int i = n / 100, jj = (n / 10) % 10, k = n % 10;
      AxisTap t0 = axis_tap(i, scZ0, S0), t1 = axis_tap(jj, scZ1, S1), t2 = axis_tap(k, scZ2, S2);
      const float* br = Bs + (((size_t)(b * 20 + 2 * i) * 20 + 2 * jj) * 20 + 2 * k) * 64 + lane;
      const int DX = 20 * 20 * 64, DY = 20 * 64, DZ = 64;
      float x = trilerp_vals(br[0], br[DX], br[DY], br[DX + DY],
                             br[DZ], br[DX + DZ], br[DY + DZ], br[DX + DY + DZ],
                             t0.w, t1.w, t2.w);
      float ss = x * x;
      for (int o = 32; o; o >>= 1) ss += __shfl_xor(ss, o, 64);
      float nrm = sqrtf(ss);
      EMB_ZN[((size_t)b * kNZ + n) * 64 + lane] = x / fmaxf(nrm, 1e-12f);
      if (lane == 0) {
        float c0, c1, c2;
        coord_exact(i, jj, k, scZ0, scZ1, scZ2, j0, j2, j4, S0, S1, S2, c0, c1, c2);
        size_t o3 = ((size_t)b * kNZ + n) * 3;
        COORD_Z[o3] = c0; COORD_Z[o3 + 1] = c1; COORD_Z[o3 + 2] = c2;
      }
    }
  }
  grid_barrier(cnt, ++gen);

  // ---- clustering: W, U, W, U, W, U, W ----
  for (int it = 0; it < 4; ++it) {
    if (blk < 250) {
      int b = blk / 125;
      for (int t = threadIdx.x; t < kNP * 64; t += 256) {
        int p = t >> 6, c = t & 63;
        pnT[c * 129 + p] = EMB_PN[((size_t)b * kNP + p) * 64 + c];
      }
      for (int t = threadIdx.x; t < kNP; t += 256) {
        cpx[t] = COORD_P[((size_t)b * kNP + t) * 3 + 0];
        cpy[t] = COORD_P[((size_t)b * kNP + t) * 3 + 1];
        cpz[t] = COORD_P[((size_t)b * kNP + t) * 3 + 2];
      }
      __syncthreads();
      bool v1 = lane < (kNP - 64);
      for (int half = 0; half < 2; ++half) {
        int chunk = (blk * 2 + half) % 250;
        {
          int r = threadIdx.x >> 6, c = threadIdx.x & 63;
          en[r][c] = EMB_TN[((size_t)b * kNT + chunk * 4 + r) * 64 + c];
        }
        __syncthreads();
        int n = chunk * 4 + wv;
        float a0 = 0.f, a1 = 0.f;
#pragma unroll
        for (int c = 0; c < 64; ++c) {
          float ec = en[wv][c];
          a0 += ec * pnT[c * 129 + lane];
          a1 += ec * pnT[c * 129 + 64 + lane];
        }
        float l0 = a0 / kTempT;
        float l1 = v1 ? (a1 / kTempT) : -3.4e38f;
        float m = fmaxf(l0, l1);
        for (int o = 32; o; o >>= 1) m = fmaxf(m, __shfl_xor(m, o, 64));
        float e0 = expf(l0 - m);
        float e1 = v1 ? expf(l1 - m) : 0.f;
        float s = e0 + e1;
        for (int o = 32; o; o >>= 1) s += __shfl_xor(s, o, 64);
        float tx = COORD_T[((size_t)b * kNT + n) * 3 + 0];
        float ty = COORD_T[((size_t)b * kNT + n) * 3 + 1];
        float tz = COORD_T[((size_t)b * kNT + n) * 3 + 2];
        {
          float dx = tx - cpx[lane], dy = ty - cpy[lane], dz = tz - cpz[lane];
          float d2 = dx * dx + dy * dy + dz * dz;
          W[((size_t)b * kNT + n) * kNP + lane] = (e0 / s) * expf(-d2 / kTwoSig2);
        }
        if (v1) {
          float dx = tx - cpx[64 + lane], dy = ty - cpy[64 + lane], dz = tz - cpz[64 + lane];
          float d2 = dx * dx + dy * dy + dz * dz;
          W[((size_t)b * kNT + n) * kNP + 64 + lane] = (e1 / s) * expf(-d2 / kTwoSig2);
        }
        __syncthreads();
      }
    }
    grid_barrier(cnt, ++gen);
    if (it == 3) break;

    // update phase (bit-identical 4x250 reduction + fused normalize)
    if (blk < 250) {
      int b = blk / kNP, p = blk % kNP;
      float accE = 0.f, accC = 0.f, accD = 0.f;
      const float* Wb = W + ((size_t)b * kNT) * kNP + p;
      const float* Eb = EMB_TS + ((size_t)b * kNT) * 64;
      const float* Cb = COORD_T + ((size_t)b * kNT) * 3;
      for (int n = wv * 250; n < (wv + 1) * 250; ++n) {
        float w = Wb[(size_t)n * kNP];
        accD += w;
        accE += w * Eb[(size_t)n * 64 + lane];
        if (lane < 3) accC += w * Cb[(size_t)n * 3 + lane];
      }
      sE[wv][lane] = accE;
      if (lane < 3) sC[wv][lane] = accC;
      if (lane == 0) sD[wv] = accD;
      __syncthreads();
      if (threadIdx.x < 64) {
        float d = sD[0] + sD[1] + sD[2] + sD[3];
        float x = (sE[0][lane] + sE[1][lane] + sE[2][lane] + sE[3][lane]) / d;
        float ss = x * x;
        for (int o = 32; o; o >>= 1) ss += __shfl_xor(ss, o, 64);
        float nrm = sqrtf(ss);
        EMB_PN[((size_t)b * kNP + p) * 64 + lane] = x / fmaxf(nrm, 1e-12f);
        if (lane < 3) {
          float cc = sC[0][lane] + sC[1][lane] + sC[2][lane] + sC[3][lane];
          COORD_P[((size_t)b * kNP + p) * 3 + lane] = cc / d;
        }
      }
      __syncthreads();
    }
    grid_barrier(cnt, ++gen);
  }

  // ---- loss phase (fused argmin; per-chunk partials bit-identical) ----
  if (blk < 250) {
    int b = blk / 125;
    for (int t = threadIdx.x; t < kNP * 64; t += 256) {
      int p = t >> 6, c = t & 63;
      pnT[c * 129 + p] = EMB_PN[((size_t)b * kNP + p) * 64 + c];
    }
    for (int n = threadIdx.x; n < 1024; n += 256) {
      int pos = (n & 15) * 64 + (n >> 4);
      if (n < 1000) {
        ctT0[pos] = COORD_T[((size_t)b * kNT + n) * 3 + 0];
        ctT1[pos] = COORD_T[((size_t)b * kNT + n) * 3 + 1];
        ctT2[pos] = COORD_T[((size_t)b * kNT + n) * 3 + 2];
      } else {
        ctT0[pos] = 3.4e38f; ctT1[pos] = 3.4e38f; ctT2[pos] = 3.4e38f;
      }
    }
    __syncthreads();
    bool v1 = lane < (kNP - 64);
    for (int half = 0; half < 2; ++half) {
      int chunk = (blk * 2 + half) % 250;
      {
        int r = threadIdx.x >> 6, c = threadIdx.x & 63;
        en[r][c] = EMB_ZN[((size_t)b * kNZ + chunk * 4 + r) * 64 + c];
      }
      __syncthreads();
      int z = chunk * 4 + wv;
      float zx = COORD_Z[((size_t)b * kNZ + z) * 3 + 0];
      float zy = COORD_Z[((size_t)b * kNZ + z) * 3 + 1];
      float zzv = COORD_Z[((size_t)b * kNZ + z) * 3 + 2];
      float best; int id;
      argmin_rowT(zx, zy, zzv, ctT0, ctT1, ctT2, lane, best, id);
      float msk = (best <= 4.0f) ? 1.0f : 0.0f;

      float a0 = 0.f, a1 = 0.f;
#pragma unroll
      for (int c = 0; c < 64; ++c) {
        float ec = en[wv][c];
        a0 += ec * pnT[c * 129 + lane];
        a1 += ec * pnT[c * 129 + 64 + lane];
      }
      float l0 = a0 / kTempS;
      float l1 = v1 ? (a1 / kTempS) : -3.4e38f;
      float m = fmaxf(l0, l1);
      for (int o = 32; o; o >>= 1) m = fmaxf(m, __shfl_xor(m, o, 64));
      float e0 = expf(l0 - m), e1 = v1 ? expf(l1 - m) : 0.f;
      float s = e0 + e1;
      for (int o = 32; o; o >>= 1) s += __shfl_xor(s, o, 64);
      float lt0 = fminf(fmaxf(logf(e0 / s + 1e-16f), -1000.0f), 0.0f);
      float r = W[((size_t)b * kNT + id) * kNP + lane] * lt0;
      if (v1) {
        float lt1 = fminf(fmaxf(logf(e1 / s + 1e-16f), -1000.0f), 0.0f);
        r += W[((size_t)b * kNT + id) * kNP + 64 + lane] * lt1;
      }
      for (int o = 32; o; o >>= 1) r += __shfl_xor(r, o, 64);
      if (lane == 0) { sR[wv] = -(r * msk); sM[wv] = msk; }
      __syncthreads();
      if (threadIdx.x == 0) {
        PART[(size_t)(b * 250 + chunk) * 2 + 0] = sR[0] + sR[1] + sR[2] + sR[3];
        PART[(size_t)(b * 250 + chunk) * 2 + 1] = sM[0] + sM[1] + sM[2] + sM[3];
      }
      __syncthreads();
    }
  }
  grid_barrier(cnt, ++gen);

  // ---- finalize (deterministic 64-lane reduce, round-3 order) ----
  if (blk == 0 && threadIdx.x < 64) {
    float loss = 0.f;
    for (int bb = 0; bb < kB; ++bb) {
      float rr = 0.f, mm = 0.f;
      for (int c2 = threadIdx.x; c2 < 250; c2 += 64) {
        rr += PART[(size_t)(bb * 250 + c2) * 2 + 0];
        mm += PART[(size_t)(bb * 250 + c2) * 2 + 1];
      }
      for (int o = 32; o; o >>= 1) {
        rr += __shfl_xor(rr, o, 64);
        mm += __shfl_xor(mm, o, 64);
      }
      loss += rr / mm;
    }
    if (threadIdx.x == 0) out[0] = loss * 0.5f;
  }
}

}  // namespace

extern "C" void kernel_launch(void* const* d_in, const int* in_sizes, int n_in,
                              void* d_out, int out_size, void* d_ws, size_t ws_size,
                              hipStream_t stream) {
  (void)in_sizes; (void)n_in; (void)out_size; (void)ws_size;
  const float* emb_s = (const float*)d_in[0];
  const float* emb_t = (const float*)d_in[1];

  float* ws = (float*)d_ws;
  float* Bt      = ws + 0;          // 1,024,000
  float* Bs      = ws + 1024000;    // 1,024,000
  float* Bp      = ws + 2048000;    // 128,000
  float* EMB_TS  = ws + 2176000;    // 128,000
  float* EMB_TN  = ws + 2304000;    // 128,000
  float* EMB_ZN  = ws + 2432000;    // 128,000
  float* EMB_PN  = ws + 2560000;    // 16,000
  float* COORD_P = ws + 2576000;    // 752
  float* COORD_T = ws + 2576752;    // 6,000
  float* COORD_Z = ws + 2582752;    // 6,000
  float* Wbuf    = ws + 2588752;    // 250,000
  float* PART    = ws + 2838752;    // 1,000
  int*   CNT     = (int*)(ws + 2839752);

  int jit[6];
  numpy_jitter_seed0(jit);
  int S0 = 80 - jit[0] - jit[1];
  int S1 = 80 - jit[2] - jit[3];
  int S2 = 80 - jit[4] - jit[5];
  float scZ0 = (float)(S0 / 10.0);
  float scZ1 = (float)(S1 / 10.0);
  float scZ2 = (float)(S2 / 10.0);

  // 1. coalesced extract into bricks (+ barrier counter reset)
  stageA_kernel<<<1800, 256, 0, stream>>>(
      emb_t, emb_s, Bt, Bs, Bp, CNT, jit[0], jit[2], jit[4], S0, S1, S2,
      scZ0, scZ1, scZ2);

  // 2. everything else in one persistent kernel (9 internal grid barriers)
  mega_kernel<<<kGrid, 256, 0, stream>>>(
      Bt, Bs, Bp, EMB_TS, EMB_TN, EMB_ZN, EMB_PN, COORD_P, COORD_T, COORD_Z,
      Wbuf, PART, (float*)d_out, CNT,
      jit[0], jit[2], jit[4], S0, S1, S2, scZ0, scZ1, scZ2);
}

// Round 5
// 124.760 us; speedup vs baseline: 3.3838x; 3.3838x over previous
//
#include <hip/hip_runtime.h>
#include <stdint.h>
#include <stddef.h>

// ClusteredPrototypeLoss — MI355X, round 5.
// 8 launches: sampler (fused gather+trilerp+norm+coords, resets counter) ->
// (wkernel -> update)x3 -> loss (+final-W recompute +argmin +finalize).
// All chaos-feeding math bit-identical to round-3 passing version.

namespace {

constexpr int kB = 2;
constexpr int kNT = 1000, kNP = 125, kNZ = 1000;
constexpr float kTempT = 0.033f, kTempS = 0.066f;
constexpr double kSig2 = (128.0 / 2.355) * (128.0 / 2.355);
constexpr float kTwoSig2 = (float)(2.0 * kSig2);

// ---------------- host: replicate np.random.default_rng(0).integers(0,8,6) ----------------
struct Pcg64 {
  __uint128_t state, inc;
  static __uint128_t mult() {
    return (((__uint128_t)2549297995355413924ULL) << 64) | 4865540595714422341ULL;
  }
  void step() { state = state * mult() + inc; }
  void seed(__uint128_t initstate, __uint128_t initseq) {
    state = 0; inc = (initseq << 1) | 1; step(); state += initstate; step();
  }
  uint64_t next64() {
    step();
    uint64_t xo = (uint64_t)(state >> 64) ^ (uint64_t)state;
    unsigned rot = (unsigned)((uint64_t)(state >> 122) & 63u);
    return (xo >> rot) | (xo << ((64u - rot) & 63u));
  }
};

static inline uint32_t ss_hashmix(uint32_t v, uint32_t& hc) {
  v ^= hc; hc *= 0x931e8875u; v *= hc; v ^= v >> 16; return v;
}
static inline uint32_t ss_mix(uint32_t x, uint32_t y) {
  uint32_t r = (0xca01f9ddu * x) ^ (0x4973f715u * y);
  r ^= r >> 16; return r;
}

static void numpy_jitter_seed0(int jit[6]) {
  uint32_t pool[4];
  uint32_t hc = 0x43b0d7e5u;  // INIT_A
  for (int i = 0; i < 4; ++i) pool[i] = ss_hashmix(0u, hc);
  for (int s = 0; s < 4; ++s)
    for (int d = 0; d < 4; ++d)
      if (s != d) pool[d] = ss_mix(pool[d], ss_hashmix(pool[s], hc));
  uint32_t w32[8];
  uint32_t hb = 0x8b51f9ddu;  // INIT_B
  for (int i = 0; i < 8; ++i) {
    uint32_t dv = pool[i & 3];
    dv ^= hb; hb *= 0x58f38dedu; dv *= hb; dv ^= dv >> 16;
    w32[i] = dv;
  }
  uint64_t w64[4];
  for (int i = 0; i < 4; ++i)
    w64[i] = (uint64_t)w32[2 * i] | ((uint64_t)w32[2 * i + 1] << 32);
  Pcg64 rng;
  rng.seed((((__uint128_t)w64[0]) << 64) | w64[1],
           (((__uint128_t)w64[2]) << 64) | w64[3]);
  for (int i = 0; i < 6; ++i) jit[i] = (int)(rng.next64() & 7ULL);
}

// ---------------- device helpers ----------------

struct AxisTap { int a, b; float w; };

__device__ inline AxisTap axis_tap(int i, float sc, int S) {
  float src = (i + 0.5f) * sc - 0.5f;
  float f = floorf(src);
  float w = src - f;
  int a = (int)f; a = a < 0 ? 0 : (a > S - 1 ? S - 1 : a);
  int b = (a + 1 > S - 1) ? S - 1 : a + 1;
  return {a, b, w};
}

__device__ inline float trilerp_vals(float v000, float v100, float v010, float v110,
                                     float v001, float v101, float v011, float v111,
                                     float w0, float w1, float w2) {
  float t00 = v000 * (1.0f - w0) + v100 * w0;
  float t10 = v010 * (1.0f - w0) + v110 * w0;
  float t01 = v001 * (1.0f - w0) + v101 * w0;
  float t11 = v011 * (1.0f - w0) + v111 * w0;
  float u0 = t00 * (1.0f - w1) + t10 * w1;
  float u1 = t01 * (1.0f - w1) + t11 * w1;
  return u0 * (1.0f - w2) + u1 * w2;
}

__device__ inline void coord_exact(int i, int j, int k,
                                   float sc0, float sc1, float sc2,
                                   int s0, int s1, int s2, int S0, int S1, int S2,
                                   float& c0o, float& c1o, float& c2o) {
#pragma clang fp contract(off)
  float src0 = (i + 0.5f) * sc0 - 0.5f;
  float f0 = floorf(src0); float w0 = src0 - f0;
  int a0 = (int)f0; a0 = a0 < 0 ? 0 : (a0 > S0 - 1 ? S0 - 1 : a0);
  int b0 = (a0 + 1 > S0 - 1) ? S0 - 1 : a0 + 1;

  float src1 = (j + 0.5f) * sc1 - 0.5f;
  float f1 = floorf(src1); float w1 = src1 - f1;
  int a1 = (int)f1; a1 = a1 < 0 ? 0 : (a1 > S1 - 1 ? S1 - 1 : a1);
  int b1 = (a1 + 1 > S1 - 1) ? S1 - 1 : a1 + 1;

  float src2 = (k + 0.5f) * sc2 - 0.5f;
  float f2 = floorf(src2); float w2 = src2 - f2;
  int a2 = (int)f2; a2 = a2 < 0 ? 0 : (a2 > S2 - 1 ? S2 - 1 : a2);
  int b2 = (a2 + 1 > S2 - 1) ? S2 - 1 : a2 + 1;

  float v0 = (float)(s0 + a0), v1 = (float)(s0 + b0);
  float c0 = v0 * (1.0f - w0) + v1 * w0;
  c0 = c0 * (1.0f - w1) + c0 * w1;
  c0 = c0 * (1.0f - w2) + c0 * w2;

  float g0 = (float)(s1 + a1), g1 = (float)(s1 + b1);
  float gA = g0 * (1.0f - w0) + g0 * w0;
  float gB = g1 * (1.0f - w0) + g1 * w0;
  float c1 = gA * (1.0f - w1) + gB * w1;
  c1 = c1 * (1.0f - w2) + c1 * w2;

  float h0 = (float)(s2 + a2), h1 = (float)(s2 + b2);
  float hA = h0 * (1.0f - w0) + h0 * w0;
  float hB = h1 * (1.0f - w0) + h1 * w0;
  hA = hA * (1.0f - w1) + hA * w1;
  hB = hB * (1.0f - w1) + hB * w1;
  float c2 = hA * (1.0f - w2) + hB * w2;

  c0o = c0; c1o = c1; c2o = c2;
}

__device__ inline void argmin_rowT(float zx, float zy, float zz,
                                   const float* ct0, const float* ct1, const float* ct2,
                                   int lane, float& best, int& bidx) {
#pragma clang fp contract(off)
  best = 3.4e38f; bidx = 0x7fffffff;
  for (int i = 0; i < 16; ++i) {
    float dx = zx - ct0[i * 64 + lane];
    float dy = zy - ct1[i * 64 + lane];
    float dz = zz - ct2[i * 64 + lane];
    float q0 = dx * dx, q1 = dy * dy, q2 = dz * dz;
    float d = sqrtf((q0 + q1) + q2);
    int n = lane * 16 + i;
    if (d < best) { best = d; bidx = n; }
  }
  for (int o = 32; o; o >>= 1) {
    float ob = __shfl_xor(best, o, 64);
    int oi = __shfl_xor(bidx, o, 64);
    if (ob < best || (ob == best && oi < bidx)) { best = ob; bidx = oi; }
  }
}

// ---------------- kernels ----------------

// Fused sampler: 450 blocks. Block = (family, b, i, jj); gathers its 4 (x,y)
// channel-rows into LDS, trilerps Kb z-points, normalizes, writes coords.
// Corner values are exact copies -> trilerp/norm bits identical to round-3.
__global__ __launch_bounds__(256) void sampler_kernel(
    const float* __restrict__ emb_t, const float* __restrict__ emb_s,
    float* __restrict__ EMB_TS, float* __restrict__ EMB_TN,
    float* __restrict__ EMB_ZN, float* __restrict__ EMB_PN,
    float* __restrict__ COORD_P, float* __restrict__ COORD_T,
    float* __restrict__ COORD_Z, int* __restrict__ cnt,
    int j0, int j2, int j4, int S0, int S1, int S2,
    float scZ0, float scZ1, float scZ2) {
  if (blockIdx.x == 0 && threadIdx.x == 0) atomicExch(cnt, 0);
  __shared__ float tile[4][20][64];
  __shared__ int zg[20];

  int blk = blockIdx.x;
  int fam, b, i, jj, Kb;
  float sc0, sc1, sc2; int Sa0, Sa1, Sa2, o0, o1, o2;
  const float* src;
  if (blk < 50) {
    fam = 0; int r = blk; b = r / 25; r %= 25; i = r / 5; jj = r % 5; Kb = 5;
    sc0 = sc1 = sc2 = 16.0f; Sa0 = Sa1 = Sa2 = 80; o0 = o1 = o2 = 0; src = emb_t;
  } else if (blk < 250) {
    fam = 1; int r = blk - 50; b = r / 100; r %= 100; i = r / 10; jj = r % 10; Kb = 10;
    sc0 = sc1 = sc2 = 8.0f; Sa0 = Sa1 = Sa2 = 80; o0 = o1 = o2 = 0; src = emb_t;
  } else {
    fam = 2; int r = blk - 250; b = r / 100; r %= 100; i = r / 10; jj = r % 10; Kb = 10;
    sc0 = scZ0; sc1 = scZ1; sc2 = scZ2; Sa0 = S0; Sa1 = S1; Sa2 = S2;
    o0 = j0; o1 = j2; o2 = j4; src = emb_s;
  }
  AxisTap t0 = axis_tap(i, sc0, Sa0);
  AxisTap t1 = axis_tap(jj, sc1, Sa1);
  if (threadIdx.x < (unsigned)(2 * Kb)) {
    AxisTap tz = axis_tap((int)threadIdx.x >> 1, sc2, Sa2);
    zg[threadIdx.x] = o2 + ((threadIdx.x & 1) ? tz.b : tz.a);
  }
  __syncthreads();
  int wv = threadIdx.x >> 6, lane = threadIdx.x & 63;
  {
    int dx = wv >> 1, dy = wv & 1;
    int x = o0 + (dx ? t0.b : t0.a);
    int y = o1 + (dy ? t1.b : t1.a);
    const float* row = src + ((size_t)(b * 64 + lane)) * 512000 + ((size_t)x * 80 + y) * 80;
    for (int zi = 0; zi < 2 * Kb; ++zi) tile[wv][zi][lane] = row[zg[zi]];
  }
  __syncthreads();

  for (int k = wv; k < Kb; k += 4) {
    AxisTap t2 = axis_tap(k, sc2, Sa2);
    int z0 = 2 * k, z1 = 2 * k + 1;
    float v000 = tile[0][z0][lane], v001 = tile[0][z1][lane];   // (dx=0,dy=0)
    float v010 = tile[1][z0][lane], v011 = tile[1][z1][lane];   // (dx=0,dy=1)
    float v100 = tile[2][z0][lane], v101 = tile[2][z1][lane];   // (dx=1,dy=0)
    float v110 = tile[3][z0][lane], v111 = tile[3][z1][lane];   // (dx=1,dy=1)
    float x = trilerp_vals(v000, v100, v010, v110, v001, v101, v011, v111,
                           t0.w, t1.w, t2.w);
    float ss = x * x;
    for (int o = 32; o; o >>= 1) ss += __shfl_xor(ss, o, 64);
    float nrm = sqrtf(ss);
    float xn = x / fmaxf(nrm, 1e-12f);

    if (fam == 0) {
      int p = (i * 5 + jj) * 5 + k;
      EMB_PN[((size_t)b * kNP + p) * 64 + lane] = xn;
      if (lane == 0) {
        float c0, c1, c2;
        coord_exact(i, jj, k, 16.0f, 16.0f, 16.0f, 0, 0, 0, 80, 80, 80, c0, c1, c2);
        size_t o3 = ((size_t)b * kNP + p) * 3;
        COORD_P[o3] = c0; COORD_P[o3 + 1] = c1; COORD_P[o3 + 2] = c2;
      }
    } else if (fam == 1) {
      int n = (i * 10 + jj) * 10 + k;
      EMB_TS[((size_t)b * kNT + n) * 64 + lane] = x;
      EMB_TN[((size_t)b * kNT + n) * 64 + lane] = xn;
      if (lane == 0) {
        float c0, c1, c2;
        coord_exact(i, jj, k, 8.0f, 8.0f, 8.0f, 0, 0, 0, 80, 80, 80, c0, c1, c2);
        size_t o3 = ((size_t)b * kNT + n) * 3;
        COORD_T[o3] = c0; COORD_T[o3 + 1] = c1; COORD_T[o3 + 2] = c2;
      }
    } else {
      int n = (i * 10 + jj) * 10 + k;
      EMB_ZN[((size_t)b * kNZ + n) * 64 + lane] = xn;
      if (lane == 0) {
        float c0, c1, c2;
        coord_exact(i, jj, k, scZ0, scZ1, scZ2, j0, j2, j4, S0, S1, S2, c0, c1, c2);
        size_t o3 = ((size_t)b * kNZ + n) * 3;
        COORD_Z[o3] = c0; COORD_Z[o3 + 1] = c1; COORD_Z[o3 + 2] = c2;
      }
    }
  }
}

// W kernel — round-3 verbatim (500 blocks, 1 row per wave).
__global__ __launch_bounds__(256) void wkernel(
    const float* __restrict__ embtn, const float* __restrict__ embpn,
    const float* __restrict__ coordt, const float* __restrict__ coordp,
    float* __restrict__ W) {
  __shared__ float pnT[64 * 129];
  __shared__ float en[4][64];
  __shared__ float cpx[128], cpy[128], cpz[128];
  int b = blockIdx.x / 250, chunk = blockIdx.x % 250;
  for (int t = threadIdx.x; t < kNP * 64; t += 256) {
    int p = t >> 6, c = t & 63;
    pnT[c * 129 + p] = embpn[((size_t)b * kNP + p) * 64 + c];
  }
  for (int t = threadIdx.x; t < kNP; t += 256) {
    cpx[t] = coordp[((size_t)b * kNP + t) * 3 + 0];
    cpy[t] = coordp[((size_t)b * kNP + t) * 3 + 1];
    cpz[t] = coordp[((size_t)b * kNP + t) * 3 + 2];
  }
  {
    int r = threadIdx.x >> 6, c = threadIdx.x & 63;
    en[r][c] = embtn[((size_t)b * kNT + chunk * 4 + r) * 64 + c];
  }
  __syncthreads();
  int wv = threadIdx.x >> 6, lane = threadIdx.x & 63;
  bool v1 = lane < (kNP - 64);
  int n = chunk * 4 + wv;
  float a0 = 0.f, a1 = 0.f;
#pragma unroll
  for (int c = 0; c < 64; ++c) {
    float ec = en[wv][c];
    a0 += ec * pnT[c * 129 + lane];
    a1 += ec * pnT[c * 129 + 64 + lane];
  }
  float l0 = a0 / kTempT;
  float l1 = v1 ? (a1 / kTempT) : -3.4e38f;
  float m = fmaxf(l0, l1);
  for (int o = 32; o; o >>= 1) m = fmaxf(m, __shfl_xor(m, o, 64));
  float e0 = expf(l0 - m);
  float e1 = v1 ? expf(l1 - m) : 0.f;
  float s = e0 + e1;
  for (int o = 32; o; o >>= 1) s += __shfl_xor(s, o, 64);
  float tx = coordt[((size_t)b * kNT + n) * 3 + 0];
  float ty = coordt[((size_t)b * kNT + n) * 3 + 1];
  float tz = coordt[((size_t)b * kNT + n) * 3 + 2];
  {
    float dx = tx - cpx[lane], dy = ty - cpy[lane], dz = tz - cpz[lane];
    float d2 = dx * dx + dy * dy + dz * dz;
    W[((size_t)b * kNT + n) * kNP + lane] = (e0 / s) * expf(-d2 / kTwoSig2);
  }
  if (v1) {
    float dx = tx - cpx[64 + lane], dy = ty - cpy[64 + lane], dz = tz - cpz[64 + lane];
    float d2 = dx * dx + dy * dy + dz * dz;
    W[((size_t)b * kNT + n) * kNP + 64 + lane] = (e1 / s) * expf(-d2 / kTwoSig2);
  }
}

// Update: batched loads (10-wide), accumulation order bit-identical to
// round-3 (n ascending per accumulator, same FMA expressions).
__global__ __launch_bounds__(256) void update_kernel(
    const float* __restrict__ W, const float* __restrict__ embts,
    const float* __restrict__ coordt, float* __restrict__ embpn,
    float* __restrict__ coordp) {
  int bp = blockIdx.x; int b = bp / kNP; int p = bp % kNP;
  int wv = threadIdx.x >> 6, lane = threadIdx.x & 63;
  float accE = 0.f, accC = 0.f, accD = 0.f;
  const float* Wb = W + ((size_t)b * kNT) * kNP + p;
  const float* Eb = embts + ((size_t)b * kNT) * 64;
  const float* Cb = coordt + ((size_t)b * kNT) * 3;
  for (int n0 = wv * 250; n0 < (wv + 1) * 250; n0 += 10) {
    float w[10], e[10], cc[10];
#pragma unroll
    for (int u = 0; u < 10; ++u) w[u] = Wb[(size_t)(n0 + u) * kNP];
#pragma unroll
    for (int u = 0; u < 10; ++u) e[u] = Eb[(size_t)(n0 + u) * 64 + lane];
    if (lane < 3) {
#pragma unroll
      for (int u = 0; u < 10; ++u) cc[u] = Cb[(size_t)(n0 + u) * 3 + lane];
    }
#pragma unroll
    for (int u = 0; u < 10; ++u) {
      accD += w[u];
      accE += w[u] * e[u];
      if (lane < 3) accC += w[u] * cc[u];
    }
  }
  __shared__ float sE[4][64];
  __shared__ float sC[4][3];
  __shared__ float sD[4];
  sE[wv][lane] = accE;
  if (lane < 3) sC[wv][lane] = accC;
  if (lane == 0) sD[wv] = accD;
  __syncthreads();
  if (threadIdx.x < 64) {
    float d = sD[0] + sD[1] + sD[2] + sD[3];
    float x = (sE[0][lane] + sE[1][lane] + sE[2][lane] + sE[3][lane]) / d;
    float ss = x * x;
    for (int o = 32; o; o >>= 1) ss += __shfl_xor(ss, o, 64);
    float nrm = sqrtf(ss);
    embpn[((size_t)b * kNP + p) * 64 + lane] = x / fmaxf(nrm, 1e-12f);
    if (lane < 3) {
      float cc2 = sC[0][lane] + sC[1][lane] + sC[2][lane] + sC[3][lane];
      coordp[((size_t)b * kNP + p) * 3 + lane] = cc2 / d;
    }
  }
}

// Loss: 500 blocks, 1 z per wave. Fused argmin + ON-THE-FLY final-W row
// recompute (bit-identical to wkernel's row math) + fused finalize.
__global__ __launch_bounds__(256) void loss_kernel(
    const float* __restrict__ embzn, const float* __restrict__ embtn,
    const float* __restrict__ embpn, const float* __restrict__ coordz,
    const float* __restrict__ coordt, const float* __restrict__ coordp,
    float* __restrict__ partials, int* __restrict__ counter,
    float* __restrict__ out) {
  __shared__ float pnT[64 * 129];
  __shared__ float ctT0[1024], ctT1[1024], ctT2[1024];
  __shared__ float en[4][64];
  __shared__ float cpx[128], cpy[128], cpz[128];
  __shared__ float sR[4], sM[4];
  int b = blockIdx.x / 250, chunk = blockIdx.x % 250;
  for (int t = threadIdx.x; t < kNP * 64; t += 256) {
    int p = t >> 6, c = t & 63;
    pnT[c * 129 + p] = embpn[((size_t)b * kNP + p) * 64 + c];
  }
  for (int t = threadIdx.x; t < kNP; t += 256) {
    cpx[t] = coordp[((size_t)b * kNP + t) * 3 + 0];
    cpy[t] = coordp[((size_t)b * kNP + t) * 3 + 1];
    cpz[t] = coordp[((size_t)b * kNP + t) * 3 + 2];
  }
  for (int n = threadIdx.x; n < 1024; n += 256) {
    int pos = (n & 15) * 64 + (n >> 4);
    if (n < 1000) {
      ctT0[pos] = coordt[((size_t)b * kNT + n) * 3 + 0];
      ctT1[pos] = coordt[((size_t)b * kNT + n) * 3 + 1];
      ctT2[pos] = coordt[((size_t)b * kNT + n) * 3 + 2];
    } else {
      ctT0[pos] = 3.4e38f; ctT1[pos] = 3.4e38f; ctT2[pos] = 3.4e38f;
    }
  }
  {
    int r = threadIdx.x >> 6, c = threadIdx.x & 63;
    en[r][c] = embzn[((size_t)b * kNZ + chunk * 4 + r) * 64 + c];
  }
  __syncthreads();
  int wv = threadIdx.x >> 6, lane = threadIdx.x & 63;
  bool v1 = lane < (kNP - 64);
  int z = chunk * 4 + wv;

  float zx = coordz[((size_t)b * kNZ + z) * 3 + 0];
  float zy = coordz[((size_t)b * kNZ + z) * 3 + 1];
  float zzv = coordz[((size_t)b * kNZ + z) * 3 + 2];
  float best; int id;
  argmin_rowT(zx, zy, zzv, ctT0, ctT1, ctT2, lane, best, id);
  float msk = (best <= 4.0f) ? 1.0f : 0.0f;

  // sim_soft row (round-3 bit-identical)
  float a0 = 0.f, a1 = 0.f;
#pragma unroll
  for (int c = 0; c < 64; ++c) {
    float ec = en[wv][c];
    a0 += ec * pnT[c * 129 + lane];
    a1 += ec * pnT[c * 129 + 64 + lane];
  }
  float l0 = a0 / kTempS;
  float l1 = v1 ? (a1 / kTempS) : -3.4e38f;
  float m = fmaxf(l0, l1);
  for (int o = 32; o; o >>= 1) m = fmaxf(m, __shfl_xor(m, o, 64));
  float e0 = expf(l0 - m), e1 = v1 ? expf(l1 - m) : 0.f;
  float s = e0 + e1;
  for (int o = 32; o; o >>= 1) s += __shfl_xor(s, o, 64);
  float lt0 = fminf(fmaxf(logf(e0 / s + 1e-16f), -1000.0f), 0.0f);
  float lt1 = 0.f;
  if (v1) lt1 = fminf(fmaxf(logf(e1 / s + 1e-16f), -1000.0f), 0.0f);

  // Recompute final-W row `id` with wkernel's exact lane math (same values,
  // same accumulation/reduction order -> identical bits).
  float ev = embtn[((size_t)b * kNT + id) * 64 + lane];
  float wa0 = 0.f, wa1 = 0.f;
#pragma unroll
  for (int c = 0; c < 64; ++c) {
    float ec = __shfl(ev, c, 64);
    wa0 += ec * pnT[c * 129 + lane];
    wa1 += ec * pnT[c * 129 + 64 + lane];
  }
  float wl0 = wa0 / kTempT;
  float wl1 = v1 ? (wa1 / kTempT) : -3.4e38f;
  float wm = fmaxf(wl0, wl1);
  for (int o = 32; o; o >>= 1) wm = fmaxf(wm, __shfl_xor(wm, o, 64));
  float we0 = expf(wl0 - wm);
  float we1 = v1 ? expf(wl1 - wm) : 0.f;
  float wsum = we0 + we1;
  for (int o = 32; o; o >>= 1) wsum += __shfl_xor(wsum, o, 64);
  int pos = (id & 15) * 64 + (id >> 4);
  float tx = ctT0[pos], ty = ctT1[pos], tz = ctT2[pos];
  float W0, W1 = 0.f;
  {
    float dx = tx - cpx[lane], dy = ty - cpy[lane], dz = tz - cpz[lane];
    float d2 = dx * dx + dy * dy + dz * dz;
    W0 = (we0 / wsum) * expf(-d2 / kTwoSig2);
  }
  if (v1) {
    float dx = tx - cpx[64 + lane], dy = ty - cpy[64 + lane], dz = tz - cpz[64 + lane];
    float d2 = dx * dx + dy * dy + dz * dz;
    W1 = (we1 / wsum) * expf(-d2 / kTwoSig2);
  }

  float r = W0 * lt0;
  if (v1) r += W1 * lt1;
  for (int o = 32; o; o >>= 1) r += __shfl_xor(r, o, 64);
  if (lane == 0) { sR[wv] = -(r * msk); sM[wv] = msk; }
  __syncthreads();
  if (threadIdx.x == 0) {
    partials[(size_t)(b * 250 + chunk) * 2 + 0] = sR[0] + sR[1] + sR[2] + sR[3];
    partials[(size_t)(b * 250 + chunk) * 2 + 1] = sM[0] + sM[1] + sM[2] + sM[3];
  }
  __syncthreads();
  __shared__ int isLast;
  if (threadIdx.x == 0) {
    __threadfence();
    isLast = (atomicAdd(counter, 1) == 499) ? 1 : 0;
  }
  __syncthreads();
  if (isLast && threadIdx.x < 64) {
    __threadfence();
    float loss = 0.f;
    for (int bb = 0; bb < kB; ++bb) {
      float rr = 0.f, mm = 0.f;
      for (int c2 = threadIdx.x; c2 < 250; c2 += 64) {
        rr += partials[(size_t)(bb * 250 + c2) * 2 + 0];
        mm += partials[(size_t)(bb * 250 + c2) * 2 + 1];
      }
      for (int o = 32; o; o >>= 1) {
        rr += __shfl_xor(rr, o, 64);
        mm += __shfl_xor(mm, o, 64);
      }
      loss += rr / mm;
    }
    if (threadIdx.x == 0) out[0] = loss * 0.5f;
  }
}

}  // namespace

extern "C" void kernel_launch(void* const* d_in, const int* in_sizes, int n_in,
                              void* d_out, int out_size, void* d_ws, size_t ws_size,
                              hipStream_t stream) {
  (void)in_sizes; (void)n_in; (void)out_size; (void)ws_size;
  const float* emb_s = (const float*)d_in[0];
  const float* emb_t = (const float*)d_in[1];

  float* ws = (float*)d_ws;
  float* EMB_TS  = ws + 0;       // 2*1000*64
  float* EMB_TN  = ws + 128000;  // 2*1000*64
  float* EMB_ZN  = ws + 256000;  // 2*1000*64
  float* EMB_PN  = ws + 384000;  // 2*125*64
  float* COORD_P = ws + 400000;  // 752
  float* COORD_T = ws + 400752;  // 6,000
  float* COORD_Z = ws + 406752;  // 6,000
  float* Wbuf    = ws + 412752;  // 250,000
  float* PART    = ws + 662752;  // 1,000
  int*   CNT     = (int*)(ws + 663752);

  int jit[6];
  numpy_jitter_seed0(jit);
  int S0 = 80 - jit[0] - jit[1];
  int S1 = 80 - jit[2] - jit[3];
  int S2 = 80 - jit[4] - jit[5];
  float scZ0 = (float)(S0 / 10.0);
  float scZ1 = (float)(S1 / 10.0);
  float scZ2 = (float)(S2 / 10.0);

  // 1. fused sampling (gather + trilerp + norm + coords; resets counter)
  sampler_kernel<<<450, 256, 0, stream>>>(
      emb_t, emb_s, EMB_TS, EMB_TN, EMB_ZN, EMB_PN, COORD_P, COORD_T, COORD_Z,
      CNT, jit[0], jit[2], jit[4], S0, S1, S2, scZ0, scZ1, scZ2);

  // 2-7. three clustering iterations
  for (int it = 0; it < 3; ++it) {
    wkernel<<<500, 256, 0, stream>>>(EMB_TN, EMB_PN, COORD_T, COORD_P, Wbuf);
    update_kernel<<<250, 256, 0, stream>>>(Wbuf, EMB_TS, COORD_T, EMB_PN, COORD_P);
  }

  // 8. loss (+final-W recompute +argmin +finalize)
  loss_kernel<<<500, 256, 0, stream>>>(EMB_ZN, EMB_TN, EMB_PN, COORD_Z, COORD_T,
                                       COORD_P, PART, CNT, (float*)d_out);
}

// Round 6
// 109.740 us; speedup vs baseline: 3.8470x; 1.1369x over previous
//
#include <hip/hip_runtime.h>
#include <stdint.h>
#include <stddef.h>

// ClusteredPrototypeLoss — MI355X, round 6.
// 8 launches: sampler (TLB-friendly gather: 16ch/wave) ->
// (wkernel 250x8rows -> update w/ LDS W-column)x3 ->
// loss (+final-W recompute +argmin +finalize).
// All chaos-feeding math bit-identical to round-5 passing version.

namespace {

constexpr int kB = 2;
constexpr int kNT = 1000, kNP = 125, kNZ = 1000;
constexpr float kTempT = 0.033f, kTempS = 0.066f;
constexpr double kSig2 = (128.0 / 2.355) * (128.0 / 2.355);
constexpr float kTwoSig2 = (float)(2.0 * kSig2);

// ---------------- host: replicate np.random.default_rng(0).integers(0,8,6) ----------------
struct Pcg64 {
  __uint128_t state, inc;
  static __uint128_t mult() {
    return (((__uint128_t)2549297995355413924ULL) << 64) | 4865540595714422341ULL;
  }
  void step() { state = state * mult() + inc; }
  void seed(__uint128_t initstate, __uint128_t initseq) {
    state = 0; inc = (initseq << 1) | 1; step(); state += initstate; step();
  }
  uint64_t next64() {
    step();
    uint64_t xo = (uint64_t)(state >> 64) ^ (uint64_t)state;
    unsigned rot = (unsigned)((uint64_t)(state >> 122) & 63u);
    return (xo >> rot) | (xo << ((64u - rot) & 63u));
  }
};

static inline uint32_t ss_hashmix(uint32_t v, uint32_t& hc) {
  v ^= hc; hc *= 0x931e8875u; v *= hc; v ^= v >> 16; return v;
}
static inline uint32_t ss_mix(uint32_t x, uint32_t y) {
  uint32_t r = (0xca01f9ddu * x) ^ (0x4973f715u * y);
  r ^= r >> 16; return r;
}

static void numpy_jitter_seed0(int jit[6]) {
  uint32_t pool[4];
  uint32_t hc = 0x43b0d7e5u;  // INIT_A
  for (int i = 0; i < 4; ++i) pool[i] = ss_hashmix(0u, hc);
  for (int s = 0; s < 4; ++s)
    for (int d = 0; d < 4; ++d)
      if (s != d) pool[d] = ss_mix(pool[d], ss_hashmix(pool[s], hc));
  uint32_t w32[8];
  uint32_t hb = 0x8b51f9ddu;  // INIT_B
  for (int i = 0; i < 8; ++i) {
    uint32_t dv = pool[i & 3];
    dv ^= hb; hb *= 0x58f38dedu; dv *= hb; dv ^= dv >> 16;
    w32[i] = dv;
  }
  uint64_t w64[4];
  for (int i = 0; i < 4; ++i)
    w64[i] = (uint64_t)w32[2 * i] | ((uint64_t)w32[2 * i + 1] << 32);
  Pcg64 rng;
  rng.seed((((__uint128_t)w64[0]) << 64) | w64[1],
           (((__uint128_t)w64[2]) << 64) | w64[3]);
  for (int i = 0; i < 6; ++i) jit[i] = (int)(rng.next64() & 7ULL);
}

// ---------------- device helpers ----------------

struct AxisTap { int a, b; float w; };

__device__ inline AxisTap axis_tap(int i, float sc, int S) {
  float src = (i + 0.5f) * sc - 0.5f;
  float f = floorf(src);
  float w = src - f;
  int a = (int)f; a = a < 0 ? 0 : (a > S - 1 ? S - 1 : a);
  int b = (a + 1 > S - 1) ? S - 1 : a + 1;
  return {a, b, w};
}

__device__ inline float trilerp_vals(float v000, float v100, float v010, float v110,
                                     float v001, float v101, float v011, float v111,
                                     float w0, float w1, float w2) {
  float t00 = v000 * (1.0f - w0) + v100 * w0;
  float t10 = v010 * (1.0f - w0) + v110 * w0;
  float t01 = v001 * (1.0f - w0) + v101 * w0;
  float t11 = v011 * (1.0f - w0) + v111 * w0;
  float u0 = t00 * (1.0f - w1) + t10 * w1;
  float u1 = t01 * (1.0f - w1) + t11 * w1;
  return u0 * (1.0f - w2) + u1 * w2;
}

__device__ inline void coord_exact(int i, int j, int k,
                                   float sc0, float sc1, float sc2,
                                   int s0, int s1, int s2, int S0, int S1, int S2,
                                   float& c0o, float& c1o, float& c2o) {
#pragma clang fp contract(off)
  float src0 = (i + 0.5f) * sc0 - 0.5f;
  float f0 = floorf(src0); float w0 = src0 - f0;
  int a0 = (int)f0; a0 = a0 < 0 ? 0 : (a0 > S0 - 1 ? S0 - 1 : a0);
  int b0 = (a0 + 1 > S0 - 1) ? S0 - 1 : a0 + 1;

  float src1 = (j + 0.5f) * sc1 - 0.5f;
  float f1 = floorf(src1); float w1 = src1 - f1;
  int a1 = (int)f1; a1 = a1 < 0 ? 0 : (a1 > S1 - 1 ? S1 - 1 : a1);
  int b1 = (a1 + 1 > S1 - 1) ? S1 - 1 : a1 + 1;

  float src2 = (k + 0.5f) * sc2 - 0.5f;
  float f2 = floorf(src2); float w2 = src2 - f2;
  int a2 = (int)f2; a2 = a2 < 0 ? 0 : (a2 > S2 - 1 ? S2 - 1 : a2);
  int b2 = (a2 + 1 > S2 - 1) ? S2 - 1 : a2 + 1;

  float v0 = (float)(s0 + a0), v1 = (float)(s0 + b0);
  float c0 = v0 * (1.0f - w0) + v1 * w0;
  c0 = c0 * (1.0f - w1) + c0 * w1;
  c0 = c0 * (1.0f - w2) + c0 * w2;

  float g0 = (float)(s1 + a1), g1 = (float)(s1 + b1);
  float gA = g0 * (1.0f - w0) + g0 * w0;
  float gB = g1 * (1.0f - w0) + g1 * w0;
  float c1 = gA * (1.0f - w1) + gB * w1;
  c1 = c1 * (1.0f - w2) + c1 * w2;

  float h0 = (float)(s2 + a2), h1 = (float)(s2 + b2);
  float hA = h0 * (1.0f - w0) + h0 * w0;
  float hB = h1 * (1.0f - w0) + h1 * w0;
  hA = hA * (1.0f - w1) + hA * w1;
  hB = hB * (1.0f - w1) + hB * w1;
  float c2 = hA * (1.0f - w2) + hB * w2;

  c0o = c0; c1o = c1; c2o = c2;
}

__device__ inline void argmin_rowT(float zx, float zy, float zz,
                                   const float* ct0, const float* ct1, const float* ct2,
                                   int lane, float& best, int& bidx) {
#pragma clang fp contract(off)
  best = 3.4e38f; bidx = 0x7fffffff;
  for (int i = 0; i < 16; ++i) {
    float dx = zx - ct0[i * 64 + lane];
    float dy = zy - ct1[i * 64 + lane];
    float dz = zz - ct2[i * 64 + lane];
    float q0 = dx * dx, q1 = dy * dy, q2 = dz * dz;
    float d = sqrtf((q0 + q1) + q2);
    int n = lane * 16 + i;
    if (d < best) { best = d; bidx = n; }
  }
  for (int o = 32; o; o >>= 1) {
    float ob = __shfl_xor(best, o, 64);
    int oi = __shfl_xor(bidx, o, 64);
    if (ob < best || (ob == best && oi < bidx)) { best = ob; bidx = oi; }
  }
}

// ---------------- kernels ----------------

// Fused sampler: 450 blocks. Block = (family, b, i, jj). TLB-friendly gather:
// each wave reads 16 channels x 4 z-segments per issue (16 pages/issue vs 64).
// tile contents identical to round-5 -> trilerp/norm bits identical.
__global__ __launch_bounds__(256) void sampler_kernel(
    const float* __restrict__ emb_t, const float* __restrict__ emb_s,
    float* __restrict__ EMB_TS, float* __restrict__ EMB_TN,
    float* __restrict__ EMB_ZN, float* __restrict__ EMB_PN,
    float* __restrict__ COORD_P, float* __restrict__ COORD_T,
    float* __restrict__ COORD_Z, int* __restrict__ cnt,
    int j0, int j2, int j4, int S0, int S1, int S2,
    float scZ0, float scZ1, float scZ2) {
  if (blockIdx.x == 0 && threadIdx.x == 0) atomicExch(cnt, 0);
  __shared__ float tile[4][20][64];
  __shared__ int zg[20];

  int blk = blockIdx.x;
  int fam, b, i, jj, Kb;
  float sc0, sc1, sc2; int Sa0, Sa1, Sa2, o0, o1, o2;
  const float* src;
  if (blk < 50) {
    fam = 0; int r = blk; b = r / 25; r %= 25; i = r / 5; jj = r % 5; Kb = 5;
    sc0 = sc1 = sc2 = 16.0f; Sa0 = Sa1 = Sa2 = 80; o0 = o1 = o2 = 0; src = emb_t;
  } else if (blk < 250) {
    fam = 1; int r = blk - 50; b = r / 100; r %= 100; i = r / 10; jj = r % 10; Kb = 10;
    sc0 = sc1 = sc2 = 8.0f; Sa0 = Sa1 = Sa2 = 80; o0 = o1 = o2 = 0; src = emb_t;
  } else {
    fam = 2; int r = blk - 250; b = r / 100; r %= 100; i = r / 10; jj = r % 10; Kb = 10;
    sc0 = scZ0; sc1 = scZ1; sc2 = scZ2; Sa0 = S0; Sa1 = S1; Sa2 = S2;
    o0 = j0; o1 = j2; o2 = j4; src = emb_s;
  }
  AxisTap t0 = axis_tap(i, sc0, Sa0);
  AxisTap t1 = axis_tap(jj, sc1, Sa1);
  if (threadIdx.x < (unsigned)(2 * Kb)) {
    AxisTap tz = axis_tap((int)threadIdx.x >> 1, sc2, Sa2);
    zg[threadIdx.x] = o2 + ((threadIdx.x & 1) ? tz.b : tz.a);
  }
  __syncthreads();
  int wv = threadIdx.x >> 6, lane = threadIdx.x & 63;
  {
    // wave = corner; lane = (zseg<<4) | chq : 16 channels x 4 z-segs per issue
    int dx = wv >> 1, dy = wv & 1;
    int x = o0 + (dx ? t0.b : t0.a);
    int y = o1 + (dy ? t1.b : t1.a);
    int chq = lane & 15, zseg = lane >> 4;
    size_t xyoff = ((size_t)x * 80 + y) * 80;
    for (int chg = 0; chg < 4; ++chg) {
      int ch = chg * 16 + chq;
      const float* row = src + ((size_t)(b * 64 + ch)) * 512000 + xyoff;
      for (int zi = zseg; zi < 2 * Kb; zi += 4) tile[wv][zi][ch] = row[zg[zi]];
    }
  }
  __syncthreads();

  for (int k = wv; k < Kb; k += 4) {
    AxisTap t2 = axis_tap(k, sc2, Sa2);
    int z0 = 2 * k, z1 = 2 * k + 1;
    float v000 = tile[0][z0][lane], v001 = tile[0][z1][lane];   // (dx=0,dy=0)
    float v010 = tile[1][z0][lane], v011 = tile[1][z1][lane];   // (dx=0,dy=1)
    float v100 = tile[2][z0][lane], v101 = tile[2][z1][lane];   // (dx=1,dy=0)
    float v110 = tile[3][z0][lane], v111 = tile[3][z1][lane];   // (dx=1,dy=1)
    float x = trilerp_vals(v000, v100, v010, v110, v001, v101, v011, v111,
                           t0.w, t1.w, t2.w);
    float ss = x * x;
    for (int o = 32; o; o >>= 1) ss += __shfl_xor(ss, o, 64);
    float nrm = sqrtf(ss);
    float xn = x / fmaxf(nrm, 1e-12f);

    if (fam == 0) {
      int p = (i * 5 + jj) * 5 + k;
      EMB_PN[((size_t)b * kNP + p) * 64 + lane] = xn;
      if (lane == 0) {
        float c0, c1, c2;
        coord_exact(i, jj, k, 16.0f, 16.0f, 16.0f, 0, 0, 0, 80, 80, 80, c0, c1, c2);
        size_t o3 = ((size_t)b * kNP + p) * 3;
        COORD_P[o3] = c0; COORD_P[o3 + 1] = c1; COORD_P[o3 + 2] = c2;
      }
    } else if (fam == 1) {
      int n = (i * 10 + jj) * 10 + k;
      EMB_TS[((size_t)b * kNT + n) * 64 + lane] = x;
      EMB_TN[((size_t)b * kNT + n) * 64 + lane] = xn;
      if (lane == 0) {
        float c0, c1, c2;
        coord_exact(i, jj, k, 8.0f, 8.0f, 8.0f, 0, 0, 0, 80, 80, 80, c0, c1, c2);
        size_t o3 = ((size_t)b * kNT + n) * 3;
        COORD_T[o3] = c0; COORD_T[o3 + 1] = c1; COORD_T[o3 + 2] = c2;
      }
    } else {
      int n = (i * 10 + jj) * 10 + k;
      EMB_ZN[((size_t)b * kNZ + n) * 64 + lane] = xn;
      if (lane == 0) {
        float c0, c1, c2;
        coord_exact(i, jj, k, scZ0, scZ1, scZ2, j0, j2, j4, S0, S1, S2, c0, c1, c2);
        size_t o3 = ((size_t)b * kNZ + n) * 3;
        COORD_Z[o3] = c0; COORD_Z[o3 + 1] = c1; COORD_Z[o3 + 2] = c2;
      }
    }
  }
}

// W kernel: 250 blocks x 8 rows (2 rows/wave, sequential). Per-row math
// bit-identical to round-5; only block<->row mapping changed.
__global__ __launch_bounds__(256) void wkernel(
    const float* __restrict__ embtn, const float* __restrict__ embpn,
    const float* __restrict__ coordt, const float* __restrict__ coordp,
    float* __restrict__ W) {
  __shared__ float pnT[64 * 129];
  __shared__ float en[8][64];
  __shared__ float cpx[128], cpy[128], cpz[128];
  int b = blockIdx.x / 125, grp = blockIdx.x % 125;
  for (int t = threadIdx.x; t < kNP * 64; t += 256) {
    int p = t >> 6, c = t & 63;
    pnT[c * 129 + p] = embpn[((size_t)b * kNP + p) * 64 + c];
  }
  for (int t = threadIdx.x; t < kNP; t += 256) {
    cpx[t] = coordp[((size_t)b * kNP + t) * 3 + 0];
    cpy[t] = coordp[((size_t)b * kNP + t) * 3 + 1];
    cpz[t] = coordp[((size_t)b * kNP + t) * 3 + 2];
  }
  for (int t = threadIdx.x; t < 8 * 64; t += 256) {
    int r = t >> 6, c = t & 63;
    en[r][c] = embtn[((size_t)b * kNT + grp * 8 + r) * 64 + c];
  }
  __syncthreads();
  int wv = threadIdx.x >> 6, lane = threadIdx.x & 63;
  bool v1 = lane < (kNP - 64);
  for (int rr = wv; rr < 8; rr += 4) {
    int n = grp * 8 + rr;
    float a0 = 0.f, a1 = 0.f;
#pragma unroll
    for (int c = 0; c < 64; ++c) {
      float ec = en[rr][c];
      a0 += ec * pnT[c * 129 + lane];
      a1 += ec * pnT[c * 129 + 64 + lane];
    }
    float l0 = a0 / kTempT;
    float l1 = v1 ? (a1 / kTempT) : -3.4e38f;
    float m = fmaxf(l0, l1);
    for (int o = 32; o; o >>= 1) m = fmaxf(m, __shfl_xor(m, o, 64));
    float e0 = expf(l0 - m);
    float e1 = v1 ? expf(l1 - m) : 0.f;
    float s = e0 + e1;
    for (int o = 32; o; o >>= 1) s += __shfl_xor(s, o, 64);
    float tx = coordt[((size_t)b * kNT + n) * 3 + 0];
    float ty = coordt[((size_t)b * kNT + n) * 3 + 1];
    float tz = coordt[((size_t)b * kNT + n) * 3 + 2];
    {
      float dx = tx - cpx[lane], dy = ty - cpy[lane], dz = tz - cpz[lane];
      float d2 = dx * dx + dy * dy + dz * dz;
      W[((size_t)b * kNT + n) * kNP + lane] = (e0 / s) * expf(-d2 / kTwoSig2);
    }
    if (v1) {
      float dx = tx - cpx[64 + lane], dy = ty - cpy[64 + lane], dz = tz - cpz[64 + lane];
      float d2 = dx * dx + dy * dy + dz * dz;
      W[((size_t)b * kNT + n) * kNP + 64 + lane] = (e1 / s) * expf(-d2 / kTwoSig2);
    }
  }
}

// Update: W column staged in LDS (same bits, broadcast reads); e-loads
// batched+pipelined. Accumulation order bit-identical to round-5.
__global__ __launch_bounds__(256) void update_kernel(
    const float* __restrict__ W, const float* __restrict__ embts,
    const float* __restrict__ coordt, float* __restrict__ embpn,
    float* __restrict__ coordp) {
  int bp = blockIdx.x; int b = bp / kNP; int p = bp % kNP;
  int wv = threadIdx.x >> 6, lane = threadIdx.x & 63;
  __shared__ float wcol[kNT];
  const float* Wb = W + ((size_t)b * kNT) * kNP + p;
  for (int n = threadIdx.x; n < kNT; n += 256) wcol[n] = Wb[(size_t)n * kNP];
  __syncthreads();

  float accE = 0.f, accC = 0.f, accD = 0.f;
  const float* Eb = embts + ((size_t)b * kNT) * 64;
  const float* Cb = coordt + ((size_t)b * kNT) * 3;
#pragma unroll 2
  for (int n0 = wv * 250; n0 < (wv + 1) * 250; n0 += 10) {
    float w[10], e[10], cc[10];
#pragma unroll
    for (int u = 0; u < 10; ++u) w[u] = wcol[n0 + u];
#pragma unroll
    for (int u = 0; u < 10; ++u) e[u] = Eb[(size_t)(n0 + u) * 64 + lane];
    if (lane < 3) {
#pragma unroll
      for (int u = 0; u < 10; ++u) cc[u] = Cb[(size_t)(n0 + u) * 3 + lane];
    }
#pragma unroll
    for (int u = 0; u < 10; ++u) {
      accD += w[u];
      accE += w[u] * e[u];
      if (lane < 3) accC += w[u] * cc[u];
    }
  }
  __shared__ float sE[4][64];
  __shared__ float sC[4][3];
  __shared__ float sD[4];
  sE[wv][lane] = accE;
  if (lane < 3) sC[wv][lane] = accC;
  if (lane == 0) sD[wv] = accD;
  __syncthreads();
  if (threadIdx.x < 64) {
    float d = sD[0] + sD[1] + sD[2] + sD[3];
    float x = (sE[0][lane] + sE[1][lane] + sE[2][lane] + sE[3][lane]) / d;
    float ss = x * x;
    for (int o = 32; o; o >>= 1) ss += __shfl_xor(ss, o, 64);
    float nrm = sqrtf(ss);
    embpn[((size_t)b * kNP + p) * 64 + lane] = x / fmaxf(nrm, 1e-12f);
    if (lane < 3) {
      float cc2 = sC[0][lane] + sC[1][lane] + sC[2][lane] + sC[3][lane];
      coordp[((size_t)b * kNP + p) * 3 + lane] = cc2 / d;
    }
  }
}

// Loss: 500 blocks, 1 z per wave. Fused argmin + on-the-fly final-W row
// recompute (bit-identical to wkernel row math) + fused finalize.
__global__ __launch_bounds__(256) void loss_kernel(
    const float* __restrict__ embzn, const float* __restrict__ embtn,
    const float* __restrict__ embpn, const float* __restrict__ coordz,
    const float* __restrict__ coordt, const float* __restrict__ coordp,
    float* __restrict__ partials, int* __restrict__ counter,
    float* __restrict__ out) {
  __shared__ float pnT[64 * 129];
  __shared__ float ctT0[1024], ctT1[1024], ctT2[1024];
  __shared__ float en[4][64];
  __shared__ float cpx[128], cpy[128], cpz[128];
  __shared__ float sR[4], sM[4];
  int b = blockIdx.x / 250, chunk = blockIdx.x % 250;
  for (int t = threadIdx.x; t < kNP * 64; t += 256) {
    int p = t >> 6, c = t & 63;
    pnT[c * 129 + p] = embpn[((size_t)b * kNP + p) * 64 + c];
  }
  for (int t = threadIdx.x; t < kNP; t += 256) {
    cpx[t] = coordp[((size_t)b * kNP + t) * 3 + 0];
    cpy[t] = coordp[((size_t)b * kNP + t) * 3 + 1];
    cpz[t] = coordp[((size_t)b * kNP + t) * 3 + 2];
  }
  for (int n = threadIdx.x; n < 1024; n += 256) {
    int pos = (n & 15) * 64 + (n >> 4);
    if (n < 1000) {
      ctT0[pos] = coordt[((size_t)b * kNT + n) * 3 + 0];
      ctT1[pos] = coordt[((size_t)b * kNT + n) * 3 + 1];
      ctT2[pos] = coordt[((size_t)b * kNT + n) * 3 + 2];
    } else {
      ctT0[pos] = 3.4e38f; ctT1[pos] = 3.4e38f; ctT2[pos] = 3.4e38f;
    }
  }
  {
    int r = threadIdx.x >> 6, c = threadIdx.x & 63;
    en[r][c] = embzn[((size_t)b * kNZ + chunk * 4 + r) * 64 + c];
  }
  __syncthreads();
  int wv = threadIdx.x >> 6, lane = threadIdx.x & 63;
  bool v1 = lane < (kNP - 64);
  int z = chunk * 4 + wv;

  float zx = coordz[((size_t)b * kNZ + z) * 3 + 0];
  float zy = coordz[((size_t)b * kNZ + z) * 3 + 1];
  float zzv = coordz[((size_t)b * kNZ + z) * 3 + 2];
  float best; int id;
  argmin_rowT(zx, zy, zzv, ctT0, ctT1, ctT2, lane, best, id);
  float msk = (best <= 4.0f) ? 1.0f : 0.0f;

  // sim_soft row (bit-identical)
  float a0 = 0.f, a1 = 0.f;
#pragma unroll
  for (int c = 0; c < 64; ++c) {
    float ec = en[wv][c];
    a0 += ec * pnT[c * 129 + lane];
    a1 += ec * pnT[c * 129 + 64 + lane];
  }
  float l0 = a0 / kTempS;
  float l1 = v1 ? (a1 / kTempS) : -3.4e38f;
  float m = fmaxf(l0, l1);
  for (int o = 32; o; o >>= 1) m = fmaxf(m, __shfl_xor(m, o, 64));
  float e0 = expf(l0 - m), e1 = v1 ? expf(l1 - m) : 0.f;
  float s = e0 + e1;
  for (int o = 32; o; o >>= 1) s += __shfl_xor(s, o, 64);
  float lt0 = fminf(fmaxf(logf(e0 / s + 1e-16f), -1000.0f), 0.0f);
  float lt1 = 0.f;
  if (v1) lt1 = fminf(fmaxf(logf(e1 / s + 1e-16f), -1000.0f), 0.0f);

  // Recompute final-W row `id` with wkernel's exact lane math.
  float ev = embtn[((size_t)b * kNT + id) * 64 + lane];
  float wa0 = 0.f, wa1 = 0.f;
#pragma unroll
  for (int c = 0; c < 64; ++c) {
    float ec = __shfl(ev, c, 64);
    wa0 += ec * pnT[c * 129 + lane];
    wa1 += ec * pnT[c * 129 + 64 + lane];
  }
  float wl0 = wa0 / kTempT;
  float wl1 = v1 ? (wa1 / kTempT) : -3.4e38f;
  float wm = fmaxf(wl0, wl1);
  for (int o = 32; o; o >>= 1) wm = fmaxf(wm, __shfl_xor(wm, o, 64));
  float we0 = expf(wl0 - wm);
  float we1 = v1 ? expf(wl1 - wm) : 0.f;
  float wsum = we0 + we1;
  for (int o = 32; o; o >>= 1) wsum += __shfl_xor(wsum, o, 64);
  int pos = (id & 15) * 64 + (id >> 4);
  float tx = ctT0[pos], ty = ctT1[pos], tz = ctT2[pos];
  float W0, W1 = 0.f;
  {
    float dx = tx - cpx[lane], dy = ty - cpy[lane], dz = tz - cpz[lane];
    float d2 = dx * dx + dy * dy + dz * dz;
    W0 = (we0 / wsum) * expf(-d2 / kTwoSig2);
  }
  if (v1) {
    float dx = tx - cpx[64 + lane], dy = ty - cpy[64 + lane], dz = tz - cpz[64 + lane];
    float d2 = dx * dx + dy * dy + dz * dz;
    W1 = (we1 / wsum) * expf(-d2 / kTwoSig2);
  }

  float r = W0 * lt0;
  if (v1) r += W1 * lt1;
  for (int o = 32; o; o >>= 1) r += __shfl_xor(r, o, 64);
  if (lane == 0) { sR[wv] = -(r * msk); sM[wv] = msk; }
  __syncthreads();
  if (threadIdx.x == 0) {
    partials[(size_t)(b * 250 + chunk) * 2 + 0] = sR[0] + sR[1] + sR[2] + sR[3];
    partials[(size_t)(b * 250 + chunk) * 2 + 1] = sM[0] + sM[1] + sM[2] + sM[3];
  }
  __syncthreads();
  __shared__ int isLast;
  if (threadIdx.x == 0) {
    __threadfence();
    isLast = (atomicAdd(counter, 1) == 499) ? 1 : 0;
  }
  __syncthreads();
  if (isLast && threadIdx.x < 64) {
    __threadfence();
    float loss = 0.f;
    for (int bb = 0; bb < kB; ++bb) {
      float rr = 0.f, mm = 0.f;
      for (int c2 = threadIdx.x; c2 < 250; c2 += 64) {
        rr += partials[(size_t)(bb * 250 + c2) * 2 + 0];
        mm += partials[(size_t)(bb * 250 + c2) * 2 + 1];
      }
      for (int o = 32; o; o >>= 1) {
        rr += __shfl_xor(rr, o, 64);
        mm += __shfl_xor(mm, o, 64);
      }
      loss += rr / mm;
    }
    if (threadIdx.x == 0) out[0] = loss * 0.5f;
  }
}

}  // namespace

extern "C" void kernel_launch(void* const* d_in, const int* in_sizes, int n_in,
                              void* d_out, int out_size, void* d_ws, size_t ws_size,
                              hipStream_t stream) {
  (void)in_sizes; (void)n_in; (void)out_size; (void)ws_size;
  const float* emb_s = (const float*)d_in[0];
  const float* emb_t = (const float*)d_in[1];

  float* ws = (float*)d_ws;
  float* EMB_TS  = ws + 0;       // 2*1000*64
  float* EMB_TN  = ws + 128000;  // 2*1000*64
  float* EMB_ZN  = ws + 256000;  // 2*1000*64
  float* EMB_PN  = ws + 384000;  // 2*125*64
  float* COORD_P = ws + 400000;  // 752
  float* COORD_T = ws + 400752;  // 6,000
  float* COORD_Z = ws + 406752;  // 6,000
  float* Wbuf    = ws + 412752;  // 250,000
  float* PART    = ws + 662752;  // 1,000
  int*   CNT     = (int*)(ws + 663752);

  int jit[6];
  numpy_jitter_seed0(jit);
  int S0 = 80 - jit[0] - jit[1];
  int S1 = 80 - jit[2] - jit[3];
  int S2 = 80 - jit[4] - jit[5];
  float scZ0 = (float)(S0 / 10.0);
  float scZ1 = (float)(S1 / 10.0);
  float scZ2 = (float)(S2 / 10.0);

  // 1. fused sampling (gather + trilerp + norm + coords; resets counter)
  sampler_kernel<<<450, 256, 0, stream>>>(
      emb_t, emb_s, EMB_TS, EMB_TN, EMB_ZN, EMB_PN, COORD_P, COORD_T, COORD_Z,
      CNT, jit[0], jit[2], jit[4], S0, S1, S2, scZ0, scZ1, scZ2);

  // 2-7. three clustering iterations
  for (int it = 0; it < 3; ++it) {
    wkernel<<<250, 256, 0, stream>>>(EMB_TN, EMB_PN, COORD_T, COORD_P, Wbuf);
    update_kernel<<<250, 256, 0, stream>>>(Wbuf, EMB_TS, COORD_T, EMB_PN, COORD_P);
  }

  // 8. loss (+final-W recompute +argmin +finalize)
  loss_kernel<<<500, 256, 0, stream>>>(EMB_ZN, EMB_TN, EMB_PN, COORD_Z, COORD_T,
                                       COORD_P, PART, CNT, (float*)d_out);
}